// Round 7
// baseline (60.954 us; speedup 1.0000x reference)
//
#include <hip/hip_runtime.h>

#define BATCH   16
#define NANCH   25200
#define TPB     1024
#define NWAVES  (TPB / 64)
#define MAXK    50
#define PRETOPK 2048
#define CONF_T  0.25f
#define IOU_T   0.45f
#define NEGV    -1000000000.0f
#define T0      0.9905f   // fixed collect threshold: E[cnt]=239, P(cnt>CAP)~8e-8
#define CAP     320       // candidate capacity (5 waves for rank)
#define SPLIT   16        // K1 blocks per batch
#define K1B     256
#define PERBLK  1575      // NANCH / SPLIT (exact)

// key: [score_bits:32][zeros:16][65535-idx:16]; u64 desc == (score desc, idx asc).
// idx < 65536 and unique -> keys unique; pad key 0 sorts last.
__device__ __forceinline__ unsigned long long make_key(float s, int idx) {
    return ((unsigned long long)__float_as_uint(s) << 32) |
           (unsigned long long)(65535 - idx);
}

// K1: full-machine candidate collection. 256 blocks; block (b,s) scans a
// 1575-anchor slice of batch b, appends keys of scores > T0 to d_ws.
__global__ __launch_bounds__(K1B) void collect_kernel(const float* __restrict__ x,
                                                      unsigned long long* __restrict__ gkeys,
                                                      unsigned int* __restrict__ gcnt) {
    const int b    = blockIdx.x >> 4;
    const int s    = blockIdx.x & 15;
    const int base = s * PERBLK;
    const float* __restrict__ xb = x + (size_t)b * NANCH * 6;

    float v[7];
    int   id[7];
    #pragma unroll
    for (int k = 0; k < 7; ++k) {          // 7*256 = 1792 >= 1575; MLP-7
        const int i = base + (int)threadIdx.x + k * K1B;
        id[k] = i;
        v[k]  = (i < base + PERBLK) ? xb[(size_t)i * 6 + 4] : 0.f;
    }
    #pragma unroll
    for (int k = 0; k < 7; ++k) {
        if (v[k] > T0) {
            unsigned slot = atomicAdd(&gcnt[b], 1u);
            if (slot < CAP) gkeys[(size_t)b * CAP + slot] = make_key(v[k], id[k]);
        }
    }
}

// K2: one workgroup per batch. Fast path: stage ~240 keys from ws ->
// counting-rank (exact lax.top_k tie order) + row gather -> 64-wide tile
// greedy (R5/R6-validated). Fallback (exact, never taken here): stage all
// scores from global, R1-validated iterative argmax with 2048-pop budget.
__global__ __launch_bounds__(TPB, 1) void nms_kernel(const float* __restrict__ x,
                                                     const unsigned long long* __restrict__ gkeys,
                                                     const unsigned int* __restrict__ gcnt,
                                                     float* __restrict__ out) {
    __shared__ float s_scores[NANCH];                 // 100800 B (fallback only)
    __shared__ unsigned long long s_keys[CAP];        //   2560 B
    __shared__ float s_srows[CAP][8];                 //  10240 B (b128-aligned rows)
    __shared__ float s_kx1[MAXK], s_ky1[MAXK], s_kx2[MAXK], s_ky2[MAXK], s_ka[MAXK];
    __shared__ float s_wval[NWAVES];
    __shared__ int   s_widx[NWAVES];
    __shared__ int   s_nk, s_best;

    const int b    = blockIdx.x;
    const int tid  = threadIdx.x;
    const int lane = tid & 63;
    const int wave = tid >> 6;

    const float* __restrict__ xb = x + (size_t)b * NANCH * 6;
    float* __restrict__ ob       = out + (size_t)b * MAXK * 6;

    const unsigned cntg = gcnt ? gcnt[b] : 0xFFFFFFFFu;  // null ws -> force fallback
    const bool fast = cntg <= CAP;
    const int  cnt  = fast ? (int)cntg : 0;

    if (tid == 0) s_nk = 0;
    if (tid < CAP) s_keys[tid] = (fast && tid < cnt) ? gkeys[(size_t)b * CAP + tid] : 0ULL;
    __syncthreads();

    if (fast) {
        // ---- counting-rank + rank-ordered row gather (threads 0..319) ----
        if (tid < CAP) {
            const unsigned long long mykey = s_keys[tid];
            float2 r0, r1, r2;
            const bool real = tid < cnt;
            if (real) {   // issue row fetch early; hides under rank loop
                int myi = 65535 - (int)(mykey & 0xFFFFULL);
                const float2* rp = (const float2*)(xb + (size_t)myi * 6);
                r0 = rp[0]; r1 = rp[1]; r2 = rp[2];
            }
            int r = 0;
            #pragma unroll 4
            for (int j = 0; j < CAP; ++j) r += (s_keys[j] > mykey) ? 1 : 0;
            if (real) {
                s_srows[r][0] = r0.x; s_srows[r][1] = r0.y;
                s_srows[r][2] = r1.x; s_srows[r][3] = r1.y;
                s_srows[r][4] = r2.x; s_srows[r][5] = r2.y;
            }
        }
        __syncthreads();

        // ---- wave 0: 64-wide tile greedy over sorted rows ----
        if (wave == 0) {
            int nk = 0;
            for (int tb = 0; tb < cnt && nk < MAXK; tb += 64) {
                const int lim = (cnt - tb) < 64 ? (cnt - tb) : 64;
                float4 bx = {0.f, 0.f, 0.f, 0.f};
                float2 be = {0.f, 0.f};
                bool sup = lane >= lim;
                if (!sup) {
                    bx = *(const float4*)&s_srows[tb + lane][0];
                    be = *(const float2*)&s_srows[tb + lane][4];
                }
                const float ba = fmaxf(bx.z - bx.x, 0.f) * fmaxf(bx.w - bx.y, 0.f);

                // (A) vs previously-kept boxes (empty on 1st tile)
                for (int j = 0; j < nk; ++j) {
                    float iw = fmaxf(fminf(bx.z, s_kx2[j]) - fmaxf(bx.x, s_kx1[j]), 0.f);
                    float ih = fmaxf(fminf(bx.w, s_ky2[j]) - fmaxf(bx.y, s_ky1[j]), 0.f);
                    float inter = iw * ih;
                    sup = sup || (inter / fmaxf(ba + s_ka[j] - inter, 1e-9f)) >= IOU_T;
                }

                // (B) pairwise overlap mask within tile (symmetric; pure VALU)
                unsigned long long m = 0ULL;
                #pragma unroll 8
                for (int j = 0; j < 64; ++j) {
                    if (j >= lim) break;
                    const float4 oj = *(const float4*)&s_srows[tb + j][0];  // broadcast
                    const float oa = fmaxf(oj.z - oj.x, 0.f) * fmaxf(oj.w - oj.y, 0.f);
                    float iw = fmaxf(fminf(bx.z, oj.z) - fmaxf(bx.x, oj.x), 0.f);
                    float ih = fmaxf(fminf(bx.w, oj.w) - fmaxf(bx.y, oj.y), 0.f);
                    float inter = iw * ih;
                    bool ov = (inter / fmaxf(ba + oa - inter, 1e-9f)) >= IOU_T;
                    m |= ov ? (1ULL << j) : 0ULL;
                }
                m &= ~(1ULL << lane);

                // (C) sequential resolve with cheap ops only
                unsigned long long alive = __ballot(!sup);
                unsigned long long keepmask = 0ULL;
                while (alive != 0ULL && nk < MAXK) {
                    const int j = __builtin_ctzll(alive);
                    keepmask |= 1ULL << j;
                    ++nk;
                    const unsigned long long kill = __ballot((m >> j) & 1ULL);
                    alive &= ~(kill | (1ULL << j));
                }

                // (D) parallel write of kept rows (exact greedy order)
                if ((keepmask >> lane) & 1ULL) {
                    const int nk0 = nk - __popcll(keepmask);
                    const int pos = nk0 + __popcll(keepmask & ((1ULL << lane) - 1ULL));
                    s_kx1[pos] = bx.x; s_ky1[pos] = bx.y;
                    s_kx2[pos] = bx.z; s_ky2[pos] = bx.w; s_ka[pos] = ba;
                    ob[pos * 6 + 0] = bx.x;
                    ob[pos * 6 + 1] = bx.y;
                    ob[pos * 6 + 2] = bx.z;
                    ob[pos * 6 + 3] = bx.w;
                    ob[pos * 6 + 4] = be.x;
                    ob[pos * 6 + 5] = be.y;
                }
            }
            if (lane == 0) s_nk = nk;
        }
        __syncthreads();
    }

    // ---- fallback / continuation (exact; never taken on this data) ----
    const bool need_fb = !fast || (s_nk < MAXK);
    if (need_fb) {
        // stage scores from global; in continuation, sentinel already-processed (>T0)
        for (int i = tid; i < NANCH; i += TPB) {
            float sc = xb[(size_t)i * 6 + 4];
            bool dead = (sc <= CONF_T) || (fast && sc > T0);
            s_scores[i] = dead ? NEGV : sc;
        }
        __syncthreads();

        const int budget = fast ? (PRETOPK - (int)cntg) : PRETOPK;
        int nk = s_nk;
        for (int pop = 0; pop < budget && nk < MAXK; ++pop) {
            // two-level argmax (score desc, index asc) — R1-validated
            float bv = NEGV - 1.0f;
            int   bi = NANCH;
            for (int i = tid; i < NANCH; i += TPB) {
                float sc = s_scores[i];
                if (sc > bv) { bv = sc; bi = i; }
            }
            #pragma unroll
            for (int off = 32; off >= 1; off >>= 1) {
                float ov = __shfl_down(bv, off);
                int   oi = __shfl_down(bi, off);
                if (ov > bv || (ov == bv && oi < bi)) { bv = ov; bi = oi; }
            }
            if (lane == 0) { s_wval[wave] = bv; s_widx[wave] = bi; }
            __syncthreads();
            if (wave == 0) {
                bv = (lane < NWAVES) ? s_wval[lane] : (NEGV - 1.0f);
                bi = (lane < NWAVES) ? s_widx[lane] : NANCH;
                #pragma unroll
                for (int off = 32; off >= 1; off >>= 1) {
                    float ov = __shfl_down(bv, off);
                    int   oi = __shfl_down(bi, off);
                    if (ov > bv || (ov == bv && oi < bi)) { bv = ov; bi = oi; }
                }
                if (lane == 0) {
                    s_best = (bv > 0.5f * NEGV) ? bi : -1;
                    if (s_best >= 0) s_scores[bi] = NEGV - 1.0f;
                }
            }
            __syncthreads();
            const int best = s_best;
            if (best < 0) break;

            if (wave == 0) {
                const float bx1 = xb[(size_t)best * 6 + 0];
                const float by1 = xb[(size_t)best * 6 + 1];
                const float bx2 = xb[(size_t)best * 6 + 2];
                const float by2 = xb[(size_t)best * 6 + 3];
                const float ba  = fmaxf(bx2 - bx1, 0.0f) * fmaxf(by2 - by1, 0.0f);
                bool sup = false;
                if (lane < nk) {
                    float iw = fmaxf(fminf(bx2, s_kx2[lane]) - fmaxf(bx1, s_kx1[lane]), 0.f);
                    float ih = fmaxf(fminf(by2, s_ky2[lane]) - fmaxf(by1, s_ky1[lane]), 0.f);
                    float inter = iw * ih;
                    float uni   = ba + s_ka[lane] - inter;
                    sup = (inter / fmaxf(uni, 1e-9f)) >= IOU_T;
                }
                if (lane == 0 && __ballot(sup) == 0ULL) {
                    s_kx1[nk] = bx1; s_ky1[nk] = by1;
                    s_kx2[nk] = bx2; s_ky2[nk] = by2; s_ka[nk] = ba;
                    ob[nk * 6 + 0] = bx1;
                    ob[nk * 6 + 1] = by1;
                    ob[nk * 6 + 2] = bx2;
                    ob[nk * 6 + 3] = by2;
                    ob[nk * 6 + 4] = xb[(size_t)best * 6 + 4];
                    ob[nk * 6 + 5] = xb[(size_t)best * 6 + 5];
                    s_nk = nk + 1;
                }
            }
            __syncthreads();
            nk = s_nk;
        }
        __syncthreads();
    }

    // Fill remaining rows with -1.0.
    const int nkf = s_nk;
    for (int i = tid; i < (MAXK - nkf) * 6; i += TPB) {
        ob[nkf * 6 + i] = -1.0f;
    }
}

extern "C" void kernel_launch(void* const* d_in, const int* in_sizes, int n_in,
                              void* d_out, int out_size, void* d_ws, size_t ws_size,
                              hipStream_t stream) {
    const float* x = (const float*)d_in[0];
    float* out     = (float*)d_out;

    const size_t need = 1024 + (size_t)BATCH * CAP * sizeof(unsigned long long);
    if (d_ws != nullptr && ws_size >= need) {
        unsigned int* gcnt        = (unsigned int*)d_ws;
        unsigned long long* gkeys = (unsigned long long*)((char*)d_ws + 1024);
        hipMemsetAsync(d_ws, 0, BATCH * sizeof(unsigned int), stream);
        collect_kernel<<<BATCH * SPLIT, K1B, 0, stream>>>(x, gkeys, gcnt);
        nms_kernel<<<BATCH, TPB, 0, stream>>>(x, gkeys, gcnt, out);
    } else {
        // No workspace: exact fallback path inside nms_kernel (gcnt==nullptr).
        nms_kernel<<<BATCH, TPB, 0, stream>>>(x, nullptr, nullptr, out);
    }
}

// Round 8
// 25.874 us; speedup vs baseline: 2.3558x; 2.3558x over previous
//
#include <hip/hip_runtime.h>

#define BATCH   16
#define NANCH   25200
#define TPB     1024
#define NWAVES  (TPB / 64)
#define MAXK    50
#define PRETOPK 2048
#define CONF_T  0.25f
#define IOU_T   0.45f
#define NEGV    -1000000000.0f
#define T0      0.9905f   // fixed collect threshold: E[cnt]=239/batch
#define CAP     320       // total candidate capacity per batch
#define SPLIT   16        // K1 blocks per batch
#define K1B     256
#define PERBLK  1575      // NANCH / SPLIT (exact)
#define SCAP    128       // per-slice key capacity (E=15; P(>128) ~ 0)

// key: [score_bits:32][zeros:16][65535-idx:16]; u64 desc == (score desc, idx asc).
__device__ __forceinline__ unsigned long long make_key(float s, int idx) {
    return ((unsigned long long)__float_as_uint(s) << 32) |
           (unsigned long long)(65535 - idx);
}

// K1: full-machine candidate collection, LDS-local counting (no global
// atomics, no pre-zeroed state: each block overwrites its private ws region
// every call -> graph-replay deterministic).
__global__ __launch_bounds__(K1B) void collect_kernel(const float* __restrict__ x,
                                                      unsigned long long* __restrict__ skeys,
                                                      unsigned int* __restrict__ scnt) {
    __shared__ unsigned long long l_keys[SCAP];
    __shared__ int l_cnt;
    const int b    = blockIdx.x >> 4;
    const int s    = blockIdx.x & 15;
    const int base = s * PERBLK;
    const float* __restrict__ xb = x + (size_t)b * NANCH * 6;

    if (threadIdx.x == 0) l_cnt = 0;
    __syncthreads();

    #pragma unroll
    for (int k = 0; k < 7; ++k) {          // 7*256 = 1792 >= 1575
        const int i = base + (int)threadIdx.x + k * K1B;
        const float v = (i < base + PERBLK) ? xb[(size_t)i * 6 + 4] : 0.f;
        if (v > T0) {
            int slot = atomicAdd(&l_cnt, 1);           // LDS atomic
            if (slot < SCAP) l_keys[slot] = make_key(v, i);
        }
    }
    __syncthreads();

    const int c = l_cnt;
    if (threadIdx.x == 0) scnt[blockIdx.x] = (unsigned)c;
    const int cc = c < SCAP ? c : SCAP;
    for (int j = (int)threadIdx.x; j < cc; j += K1B)
        skeys[(size_t)blockIdx.x * SCAP + j] = l_keys[j];
}

// K2: one workgroup per batch. Fast path: gather ~240 keys from ws ->
// counting-rank (exact lax.top_k tie order) + row gather -> 64-wide tile
// greedy (R5/R6-validated). Fallback (exact, never taken here): stage all
// scores from global, R1-validated iterative argmax with 2048-pop budget.
__global__ __launch_bounds__(TPB, 1) void nms_kernel(const float* __restrict__ x,
                                                     const unsigned long long* __restrict__ skeys,
                                                     const unsigned int* __restrict__ scnt,
                                                     float* __restrict__ out) {
    __shared__ float s_scores[NANCH];                 // 100800 B (fallback only)
    __shared__ unsigned long long s_keys[CAP];        //   2560 B
    __shared__ float s_srows[CAP][8];                 //  10240 B
    __shared__ float s_kx1[MAXK], s_ky1[MAXK], s_kx2[MAXK], s_ky2[MAXK], s_ka[MAXK];
    __shared__ float s_wval[NWAVES];
    __shared__ int   s_widx[NWAVES];
    __shared__ int   s_slc[SPLIT], s_soff[SPLIT];
    __shared__ int   s_cnt, s_bad, s_nk, s_best;

    const int b    = blockIdx.x;
    const int tid  = threadIdx.x;
    const int lane = tid & 63;
    const int wave = tid >> 6;

    const float* __restrict__ xb = x + (size_t)b * NANCH * 6;
    float* __restrict__ ob       = out + (size_t)b * MAXK * 6;

    if (tid < CAP) s_keys[tid] = 0ULL;
    if (tid < SPLIT) s_slc[tid] = scnt ? (int)scnt[b * SPLIT + tid] : SCAP + 1;
    if (tid == 0) s_nk = 0;
    __syncthreads();
    if (tid == 0) {
        int off = 0, bad = 0;
        #pragma unroll
        for (int s = 0; s < SPLIT; ++s) {
            s_soff[s] = off;
            off += s_slc[s];
            bad |= (s_slc[s] > SCAP);
        }
        s_cnt = off;
        s_bad = bad | (off > CAP);
    }
    __syncthreads();

    const bool fast = !s_bad;
    const int  cnt  = fast ? s_cnt : 0;

    if (fast) {
        // gather keys compactly: wave w handles slice w
        if (wave < SPLIT) {
            const int c = s_slc[wave], o = s_soff[wave];
            for (int j = lane; j < c; j += 64)
                s_keys[o + j] = skeys[(size_t)(b * SPLIT + wave) * SCAP + j];
        }
        __syncthreads();

        // ---- counting-rank + rank-ordered row gather (threads 0..319) ----
        if (tid < CAP) {
            const unsigned long long mykey = s_keys[tid];
            float2 r0, r1, r2;
            const bool real = tid < cnt;
            if (real) {   // issue row fetch early; hides under rank loop
                int myi = 65535 - (int)(mykey & 0xFFFFULL);
                const float2* rp = (const float2*)(xb + (size_t)myi * 6);
                r0 = rp[0]; r1 = rp[1]; r2 = rp[2];
            }
            int r = 0;
            #pragma unroll 4
            for (int j = 0; j < CAP; ++j) r += (s_keys[j] > mykey) ? 1 : 0;
            if (real) {
                s_srows[r][0] = r0.x; s_srows[r][1] = r0.y;
                s_srows[r][2] = r1.x; s_srows[r][3] = r1.y;
                s_srows[r][4] = r2.x; s_srows[r][5] = r2.y;
            }
        }
        __syncthreads();

        // ---- wave 0: 64-wide tile greedy over sorted rows ----
        if (wave == 0) {
            int nk = 0;
            for (int tb = 0; tb < cnt && nk < MAXK; tb += 64) {
                const int lim = (cnt - tb) < 64 ? (cnt - tb) : 64;
                float4 bx = {0.f, 0.f, 0.f, 0.f};
                float2 be = {0.f, 0.f};
                bool sup = lane >= lim;
                if (!sup) {
                    bx = *(const float4*)&s_srows[tb + lane][0];
                    be = *(const float2*)&s_srows[tb + lane][4];
                }
                const float ba = fmaxf(bx.z - bx.x, 0.f) * fmaxf(bx.w - bx.y, 0.f);

                // (A) vs previously-kept boxes (empty on 1st tile)
                for (int j = 0; j < nk; ++j) {
                    float iw = fmaxf(fminf(bx.z, s_kx2[j]) - fmaxf(bx.x, s_kx1[j]), 0.f);
                    float ih = fmaxf(fminf(bx.w, s_ky2[j]) - fmaxf(bx.y, s_ky1[j]), 0.f);
                    float inter = iw * ih;
                    sup = sup || (inter / fmaxf(ba + s_ka[j] - inter, 1e-9f)) >= IOU_T;
                }

                // (B) pairwise overlap mask within tile (symmetric; pure VALU)
                unsigned long long m = 0ULL;
                #pragma unroll 8
                for (int j = 0; j < 64; ++j) {
                    if (j >= lim) break;
                    const float4 oj = *(const float4*)&s_srows[tb + j][0];
                    const float oa = fmaxf(oj.z - oj.x, 0.f) * fmaxf(oj.w - oj.y, 0.f);
                    float iw = fmaxf(fminf(bx.z, oj.z) - fmaxf(bx.x, oj.x), 0.f);
                    float ih = fmaxf(fminf(bx.w, oj.w) - fmaxf(bx.y, oj.y), 0.f);
                    float inter = iw * ih;
                    bool ov = (inter / fmaxf(ba + oa - inter, 1e-9f)) >= IOU_T;
                    m |= ov ? (1ULL << j) : 0ULL;
                }
                m &= ~(1ULL << lane);

                // (C) sequential resolve with cheap ops only
                unsigned long long alive = __ballot(!sup);
                unsigned long long keepmask = 0ULL;
                while (alive != 0ULL && nk < MAXK) {
                    const int j = __builtin_ctzll(alive);
                    keepmask |= 1ULL << j;
                    ++nk;
                    const unsigned long long kill = __ballot((m >> j) & 1ULL);
                    alive &= ~(kill | (1ULL << j));
                }

                // (D) parallel write of kept rows (exact greedy order)
                if ((keepmask >> lane) & 1ULL) {
                    const int nk0 = nk - __popcll(keepmask);
                    const int pos = nk0 + __popcll(keepmask & ((1ULL << lane) - 1ULL));
                    s_kx1[pos] = bx.x; s_ky1[pos] = bx.y;
                    s_kx2[pos] = bx.z; s_ky2[pos] = bx.w; s_ka[pos] = ba;
                    ob[pos * 6 + 0] = bx.x;
                    ob[pos * 6 + 1] = bx.y;
                    ob[pos * 6 + 2] = bx.z;
                    ob[pos * 6 + 3] = bx.w;
                    ob[pos * 6 + 4] = be.x;
                    ob[pos * 6 + 5] = be.y;
                }
            }
            if (lane == 0) s_nk = nk;
        }
        __syncthreads();
    }

    // ---- fallback / continuation (exact; never taken on this data) ----
    const bool need_fb = !fast || (s_nk < MAXK);
    if (need_fb) {
        // stage scores; in continuation, sentinel already-processed (>T0)
        for (int i = tid; i < NANCH; i += TPB) {
            float sc = xb[(size_t)i * 6 + 4];
            bool dead = (sc <= CONF_T) || (fast && sc > T0);
            s_scores[i] = dead ? NEGV : sc;
        }
        __syncthreads();

        const int budget = fast ? (PRETOPK - cnt) : PRETOPK;
        int nk = s_nk;
        for (int pop = 0; pop < budget && nk < MAXK; ++pop) {
            // two-level argmax (score desc, index asc) — R1-validated
            float bv = NEGV - 1.0f;
            int   bi = NANCH;
            for (int i = tid; i < NANCH; i += TPB) {
                float sc = s_scores[i];
                if (sc > bv) { bv = sc; bi = i; }
            }
            #pragma unroll
            for (int off = 32; off >= 1; off >>= 1) {
                float ov = __shfl_down(bv, off);
                int   oi = __shfl_down(bi, off);
                if (ov > bv || (ov == bv && oi < bi)) { bv = ov; bi = oi; }
            }
            if (lane == 0) { s_wval[wave] = bv; s_widx[wave] = bi; }
            __syncthreads();
            if (wave == 0) {
                bv = (lane < NWAVES) ? s_wval[lane] : (NEGV - 1.0f);
                bi = (lane < NWAVES) ? s_widx[lane] : NANCH;
                #pragma unroll
                for (int off = 32; off >= 1; off >>= 1) {
                    float ov = __shfl_down(bv, off);
                    int   oi = __shfl_down(bi, off);
                    if (ov > bv || (ov == bv && oi < bi)) { bv = ov; bi = oi; }
                }
                if (lane == 0) {
                    s_best = (bv > 0.5f * NEGV) ? bi : -1;
                    if (s_best >= 0) s_scores[bi] = NEGV - 1.0f;
                }
            }
            __syncthreads();
            const int best = s_best;
            if (best < 0) break;

            if (wave == 0) {
                const float bx1 = xb[(size_t)best * 6 + 0];
                const float by1 = xb[(size_t)best * 6 + 1];
                const float bx2 = xb[(size_t)best * 6 + 2];
                const float by2 = xb[(size_t)best * 6 + 3];
                const float ba  = fmaxf(bx2 - bx1, 0.0f) * fmaxf(by2 - by1, 0.0f);
                bool sup = false;
                if (lane < nk) {
                    float iw = fmaxf(fminf(bx2, s_kx2[lane]) - fmaxf(bx1, s_kx1[lane]), 0.f);
                    float ih = fmaxf(fminf(by2, s_ky2[lane]) - fmaxf(by1, s_ky1[lane]), 0.f);
                    float inter = iw * ih;
                    float uni   = ba + s_ka[lane] - inter;
                    sup = (inter / fmaxf(uni, 1e-9f)) >= IOU_T;
                }
                if (lane == 0 && __ballot(sup) == 0ULL) {
                    s_kx1[nk] = bx1; s_ky1[nk] = by1;
                    s_kx2[nk] = bx2; s_ky2[nk] = by2; s_ka[nk] = ba;
                    ob[nk * 6 + 0] = bx1;
                    ob[nk * 6 + 1] = by1;
                    ob[nk * 6 + 2] = bx2;
                    ob[nk * 6 + 3] = by2;
                    ob[nk * 6 + 4] = xb[(size_t)best * 6 + 4];
                    ob[nk * 6 + 5] = xb[(size_t)best * 6 + 5];
                    s_nk = nk + 1;
                }
            }
            __syncthreads();
            nk = s_nk;
        }
        __syncthreads();
    }

    // Fill remaining rows with -1.0.
    const int nkf = s_nk;
    for (int i = tid; i < (MAXK - nkf) * 6; i += TPB) {
        ob[nkf * 6 + i] = -1.0f;
    }
}

extern "C" void kernel_launch(void* const* d_in, const int* in_sizes, int n_in,
                              void* d_out, int out_size, void* d_ws, size_t ws_size,
                              hipStream_t stream) {
    const float* x = (const float*)d_in[0];
    float* out     = (float*)d_out;

    const size_t cnt_bytes = (size_t)BATCH * SPLIT * sizeof(unsigned int);   // 1 KB
    const size_t key_bytes = (size_t)BATCH * SPLIT * SCAP * sizeof(unsigned long long);
    if (d_ws != nullptr && ws_size >= 1024 + key_bytes) {
        unsigned int* scnt        = (unsigned int*)d_ws;
        unsigned long long* skeys = (unsigned long long*)((char*)d_ws + 1024);
        (void)cnt_bytes;
        collect_kernel<<<BATCH * SPLIT, K1B, 0, stream>>>(x, skeys, scnt);
        nms_kernel<<<BATCH, TPB, 0, stream>>>(x, skeys, scnt, out);
    } else {
        // No workspace: exact fallback path inside nms_kernel.
        nms_kernel<<<BATCH, TPB, 0, stream>>>(x, nullptr, nullptr, out);
    }
}

// Round 9
// 25.373 us; speedup vs baseline: 2.4023x; 1.0197x over previous
//
#include <hip/hip_runtime.h>

#define BATCH   16
#define NANCH   25200
#define TPB     512
#define NWAVES  (TPB / 64)
#define MAXK    50
#define PRETOPK 2048
#define CONF_T  0.25f
#define IOU_T   0.45f
#define NEGV    -1000000000.0f
#define T0      0.9905f   // fixed collect threshold: E[cnt]=239/batch
#define CAP     320       // total candidate capacity per batch
#define SPLIT   32        // K1 slices per batch
#define K1B     256
#define PERBLK  788       // ceil(NANCH/SPLIT); last slice bounded by NANCH
#define SCAP    96        // per-slice key capacity (E=7.5; P(>96) ~ 0)

// key: [score_bits:32][zeros:16][65535-idx:16]; u64 desc == (score desc, idx asc).
__device__ __forceinline__ unsigned long long make_key(float s, int idx) {
    return ((unsigned long long)__float_as_uint(s) << 32) |
           (unsigned long long)(65535 - idx);
}

// K1: full-machine candidate collection (512 blocks, 2/CU). LDS-local count,
// private ws region per block fully rewritten every call -> replay-safe.
__global__ __launch_bounds__(K1B) void collect_kernel(const float* __restrict__ x,
                                                      unsigned long long* __restrict__ skeys,
                                                      unsigned int* __restrict__ scnt) {
    __shared__ unsigned long long l_keys[SCAP];
    __shared__ int l_cnt;
    const int b    = blockIdx.x >> 5;
    const int s    = blockIdx.x & 31;
    const int base = s * PERBLK;
    const int end  = (base + PERBLK < NANCH) ? base + PERBLK : NANCH;
    const float* __restrict__ xb = x + (size_t)b * NANCH * 6;

    if (threadIdx.x == 0) l_cnt = 0;
    __syncthreads();

    #pragma unroll
    for (int k = 0; k < 4; ++k) {          // 4*256 = 1024 >= 788
        const int i = base + (int)threadIdx.x + k * K1B;
        if (i < end) {
            const float v = xb[(size_t)i * 6 + 4];
            if (v > T0) {
                int slot = atomicAdd(&l_cnt, 1);       // LDS atomic
                if (slot < SCAP) l_keys[slot] = make_key(v, i);
            }
        }
    }
    __syncthreads();

    const int c = l_cnt;
    if (threadIdx.x == 0) scnt[blockIdx.x] = (unsigned)c;
    const int cc = c < SCAP ? c : SCAP;
    for (int j = (int)threadIdx.x; j < cc; j += K1B)
        skeys[(size_t)blockIdx.x * SCAP + j] = l_keys[j];
}

// K2: one workgroup per batch, 8 waves. Fast path: gather ~240 keys ->
// counting-rank (exact lax.top_k tie order, b128 LDS reads) + row gather ->
// 64-wide tile greedy (R5-R8 validated). Fallback (exact, never taken on
// this data): stage scores from global, iterative argmax, 2048-pop budget.
__global__ __launch_bounds__(TPB, 1) void nms_kernel(const float* __restrict__ x,
                                                     const unsigned long long* __restrict__ skeys,
                                                     const unsigned int* __restrict__ scnt,
                                                     float* __restrict__ out) {
    __shared__ float s_scores[NANCH];                      // fallback only
    __shared__ __align__(16) unsigned long long s_keys[CAP];
    __shared__ float s_srows[CAP][8];
    __shared__ float s_kx1[MAXK], s_ky1[MAXK], s_kx2[MAXK], s_ky2[MAXK], s_ka[MAXK];
    __shared__ float s_wval[NWAVES];
    __shared__ int   s_widx[NWAVES];
    __shared__ int   s_slc[SPLIT], s_soff[SPLIT];
    __shared__ int   s_cnt, s_bad, s_nk, s_best;

    const int b    = blockIdx.x;
    const int tid  = threadIdx.x;
    const int lane = tid & 63;
    const int wave = tid >> 6;

    const float* __restrict__ xb = x + (size_t)b * NANCH * 6;
    float* __restrict__ ob       = out + (size_t)b * MAXK * 6;

    if (tid < CAP) s_keys[tid] = 0ULL;
    if (tid < SPLIT) s_slc[tid] = scnt ? (int)scnt[b * SPLIT + tid] : SCAP + 1;
    if (tid == 0) s_nk = 0;
    __syncthreads();
    if (tid == 0) {
        int off = 0, bad = 0;
        #pragma unroll
        for (int s = 0; s < SPLIT; ++s) {
            s_soff[s] = off;
            off += s_slc[s];
            bad |= (s_slc[s] > SCAP);
        }
        s_cnt = off;
        s_bad = bad | (off > CAP);
    }
    __syncthreads();

    const bool fast = !s_bad;
    const int  cnt  = fast ? s_cnt : 0;

    if (fast) {
        // gather keys compactly: 16 threads per slice (32 slices x 16 = 512)
        {
            const int s = tid >> 4, j0 = tid & 15;
            const int c = s_slc[s], o = s_soff[s];
            for (int j = j0; j < c; j += 16)
                s_keys[o + j] = skeys[(size_t)(b * SPLIT + s) * SCAP + j];
        }
        __syncthreads();

        // ---- counting-rank + rank-ordered row gather (threads 0..319) ----
        if (tid < CAP) {
            const unsigned long long mykey = s_keys[tid];
            float2 r0, r1, r2;
            const bool real = tid < cnt;
            if (real) {   // issue row fetch early; hides under rank loop
                int myi = 65535 - (int)(mykey & 0xFFFFULL);
                const float2* rp = (const float2*)(xb + (size_t)myi * 6);
                r0 = rp[0]; r1 = rp[1]; r2 = rp[2];
            }
            int r = 0;
            const ulonglong2* kp = (const ulonglong2*)s_keys;
            #pragma unroll 4
            for (int j = 0; j < CAP / 2; ++j) {
                const ulonglong2 p = kp[j];
                r += (p.x > mykey) ? 1 : 0;
                r += (p.y > mykey) ? 1 : 0;
            }
            if (real) {
                s_srows[r][0] = r0.x; s_srows[r][1] = r0.y;
                s_srows[r][2] = r1.x; s_srows[r][3] = r1.y;
                s_srows[r][4] = r2.x; s_srows[r][5] = r2.y;
            }
        }
        __syncthreads();

        // ---- wave 0: 64-wide tile greedy over sorted rows ----
        if (wave == 0) {
            int nk = 0;
            for (int tb = 0; tb < cnt && nk < MAXK; tb += 64) {
                const int lim = (cnt - tb) < 64 ? (cnt - tb) : 64;
                float4 bx = {0.f, 0.f, 0.f, 0.f};
                float2 be = {0.f, 0.f};
                bool sup = lane >= lim;
                if (!sup) {
                    bx = *(const float4*)&s_srows[tb + lane][0];
                    be = *(const float2*)&s_srows[tb + lane][4];
                }
                const float ba = fmaxf(bx.z - bx.x, 0.f) * fmaxf(bx.w - bx.y, 0.f);

                // (A) vs previously-kept boxes (empty on 1st tile)
                for (int j = 0; j < nk; ++j) {
                    float iw = fmaxf(fminf(bx.z, s_kx2[j]) - fmaxf(bx.x, s_kx1[j]), 0.f);
                    float ih = fmaxf(fminf(bx.w, s_ky2[j]) - fmaxf(bx.y, s_ky1[j]), 0.f);
                    float inter = iw * ih;
                    sup = sup || (inter / fmaxf(ba + s_ka[j] - inter, 1e-9f)) >= IOU_T;
                }

                // (B) pairwise overlap mask within tile (symmetric; pure VALU)
                unsigned long long m = 0ULL;
                #pragma unroll 8
                for (int j = 0; j < 64; ++j) {
                    if (j >= lim) break;
                    const float4 oj = *(const float4*)&s_srows[tb + j][0];
                    const float oa = fmaxf(oj.z - oj.x, 0.f) * fmaxf(oj.w - oj.y, 0.f);
                    float iw = fmaxf(fminf(bx.z, oj.z) - fmaxf(bx.x, oj.x), 0.f);
                    float ih = fmaxf(fminf(bx.w, oj.w) - fmaxf(bx.y, oj.y), 0.f);
                    float inter = iw * ih;
                    bool ov = (inter / fmaxf(ba + oa - inter, 1e-9f)) >= IOU_T;
                    m |= ov ? (1ULL << j) : 0ULL;
                }
                m &= ~(1ULL << lane);

                // (C) sequential resolve with cheap ops only
                unsigned long long alive = __ballot(!sup);
                unsigned long long keepmask = 0ULL;
                while (alive != 0ULL && nk < MAXK) {
                    const int j = __builtin_ctzll(alive);
                    keepmask |= 1ULL << j;
                    ++nk;
                    const unsigned long long kill = __ballot((m >> j) & 1ULL);
                    alive &= ~(kill | (1ULL << j));
                }

                // (D) parallel write of kept rows (exact greedy order)
                if ((keepmask >> lane) & 1ULL) {
                    const int nk0 = nk - __popcll(keepmask);
                    const int pos = nk0 + __popcll(keepmask & ((1ULL << lane) - 1ULL));
                    s_kx1[pos] = bx.x; s_ky1[pos] = bx.y;
                    s_kx2[pos] = bx.z; s_ky2[pos] = bx.w; s_ka[pos] = ba;
                    ob[pos * 6 + 0] = bx.x;
                    ob[pos * 6 + 1] = bx.y;
                    ob[pos * 6 + 2] = bx.z;
                    ob[pos * 6 + 3] = bx.w;
                    ob[pos * 6 + 4] = be.x;
                    ob[pos * 6 + 5] = be.y;
                }
            }
            if (lane == 0) s_nk = nk;
        }
        __syncthreads();
    }

    // ---- fallback / continuation (exact; never taken on this data) ----
    const bool need_fb = !fast || (s_nk < MAXK);
    if (need_fb) {
        for (int i = tid; i < NANCH; i += TPB) {
            float sc = xb[(size_t)i * 6 + 4];
            bool dead = (sc <= CONF_T) || (fast && sc > T0);
            s_scores[i] = dead ? NEGV : sc;
        }
        __syncthreads();

        const int budget = fast ? (PRETOPK - cnt) : PRETOPK;
        int nk = s_nk;
        for (int pop = 0; pop < budget && nk < MAXK; ++pop) {
            float bv = NEGV - 1.0f;
            int   bi = NANCH;
            for (int i = tid; i < NANCH; i += TPB) {
                float sc = s_scores[i];
                if (sc > bv) { bv = sc; bi = i; }
            }
            #pragma unroll
            for (int off = 32; off >= 1; off >>= 1) {
                float ov = __shfl_down(bv, off);
                int   oi = __shfl_down(bi, off);
                if (ov > bv || (ov == bv && oi < bi)) { bv = ov; bi = oi; }
            }
            if (lane == 0) { s_wval[wave] = bv; s_widx[wave] = bi; }
            __syncthreads();
            if (wave == 0) {
                bv = (lane < NWAVES) ? s_wval[lane] : (NEGV - 1.0f);
                bi = (lane < NWAVES) ? s_widx[lane] : NANCH;
                #pragma unroll
                for (int off = 32; off >= 1; off >>= 1) {
                    float ov = __shfl_down(bv, off);
                    int   oi = __shfl_down(bi, off);
                    if (ov > bv || (ov == bv && oi < bi)) { bv = ov; bi = oi; }
                }
                if (lane == 0) {
                    s_best = (bv > 0.5f * NEGV) ? bi : -1;
                    if (s_best >= 0) s_scores[bi] = NEGV - 1.0f;
                }
            }
            __syncthreads();
            const int best = s_best;
            if (best < 0) break;

            if (wave == 0) {
                const float bx1 = xb[(size_t)best * 6 + 0];
                const float by1 = xb[(size_t)best * 6 + 1];
                const float bx2 = xb[(size_t)best * 6 + 2];
                const float by2 = xb[(size_t)best * 6 + 3];
                const float ba  = fmaxf(bx2 - bx1, 0.0f) * fmaxf(by2 - by1, 0.0f);
                bool sup = false;
                if (lane < nk) {
                    float iw = fmaxf(fminf(bx2, s_kx2[lane]) - fmaxf(bx1, s_kx1[lane]), 0.f);
                    float ih = fmaxf(fminf(by2, s_ky2[lane]) - fmaxf(by1, s_ky1[lane]), 0.f);
                    float inter = iw * ih;
                    float uni   = ba + s_ka[lane] - inter;
                    sup = (inter / fmaxf(uni, 1e-9f)) >= IOU_T;
                }
                if (lane == 0 && __ballot(sup) == 0ULL) {
                    s_kx1[nk] = bx1; s_ky1[nk] = by1;
                    s_kx2[nk] = bx2; s_ky2[nk] = by2; s_ka[nk] = ba;
                    ob[nk * 6 + 0] = bx1;
                    ob[nk * 6 + 1] = by1;
                    ob[nk * 6 + 2] = bx2;
                    ob[nk * 6 + 3] = by2;
                    ob[nk * 6 + 4] = xb[(size_t)best * 6 + 4];
                    ob[nk * 6 + 5] = xb[(size_t)best * 6 + 5];
                    s_nk = nk + 1;
                }
            }
            __syncthreads();
            nk = s_nk;
        }
        __syncthreads();
    }

    // Fill remaining rows with -1.0.
    const int nkf = s_nk;
    for (int i = tid; i < (MAXK - nkf) * 6; i += TPB) {
        ob[nkf * 6 + i] = -1.0f;
    }
}

extern "C" void kernel_launch(void* const* d_in, const int* in_sizes, int n_in,
                              void* d_out, int out_size, void* d_ws, size_t ws_size,
                              hipStream_t stream) {
    const float* x = (const float*)d_in[0];
    float* out     = (float*)d_out;

    const size_t key_off   = 4096;  // scnt: 512 u32 = 2KB, padded
    const size_t key_bytes = (size_t)BATCH * SPLIT * SCAP * sizeof(unsigned long long);
    if (d_ws != nullptr && ws_size >= key_off + key_bytes) {
        unsigned int* scnt        = (unsigned int*)d_ws;
        unsigned long long* skeys = (unsigned long long*)((char*)d_ws + key_off);
        collect_kernel<<<BATCH * SPLIT, K1B, 0, stream>>>(x, skeys, scnt);
        nms_kernel<<<BATCH, TPB, 0, stream>>>(x, skeys, scnt, out);
    } else {
        // No workspace: exact fallback path inside nms_kernel.
        nms_kernel<<<BATCH, TPB, 0, stream>>>(x, nullptr, nullptr, out);
    }
}